// Round 10
// baseline (1436.316 us; speedup 1.0000x reference)
//
#include <hip/hip_runtime.h>
#include <cmath>

// Problem constants (from reference)
constexpr int NN = 50000;      // nodes
constexpr int NE = 1600000;    // edges
constexpr int H  = 64;         // hidden
constexpr int NL = 5;          // layers
constexpr int NG = 4;          // graphs
constexpr int EIN = 2 * H + 5; // 133
constexpr int NIN = 2 * H;     // 128

typedef short bf16x8 __attribute__((ext_vector_type(8)));
typedef float f32x4  __attribute__((ext_vector_type(4)));

__device__ __forceinline__ float silu_f(float x) {
    return x / (1.0f + __expf(-x));
}

// round-to-nearest-even fp32 -> bf16 bits (scalar, cold paths)
__device__ __forceinline__ unsigned int f2bf(float f) {
    unsigned int u = __float_as_uint(f);
    u += 0x7fffu + ((u >> 16) & 1u);
    return u >> 16;
}
// hot-path pack: single HW instruction (RNE), x -> low half, y -> high half
__device__ __forceinline__ unsigned int pack_bf16x2(float x, float y) {
    unsigned int r;
    asm("v_cvt_pk_bf16_f32 %0, %1, %2" : "=v"(r) : "v"(x), "v"(y));
    return r;
}

// DPP lane-shift within 16-lane rows (VALU pipe, not ds_bpermute).
// row_shr:N = 0x110|N (lane i <- lane i-N within row); row_shl:1 = 0x101.
// bound_ctrl=false: out-of-row lanes keep `old`.
template <int CTRL>
__device__ __forceinline__ int dpp_i(int old, int v) {
    return __builtin_amdgcn_update_dpp(old, v, CTRL, 0xF, 0xF, false);
}

// ---------------------------------------------------------------------------
// Counting sort of edges by dst
// ---------------------------------------------------------------------------
__global__ __launch_bounds__(256) void degree_kernel(
    const int* __restrict__ ei, int* __restrict__ deg)
{
    int e = blockIdx.x * 256 + threadIdx.x;
    if (e < NE) atomicAdd(&deg[ei[NE + e]], 1);
}

__global__ __launch_bounds__(1024) void scan1_kernel(
    const int* __restrict__ deg, int* __restrict__ off, int* __restrict__ bsum)
{
    __shared__ int sh[1024];
    const int tid = threadIdx.x;
    int i = blockIdx.x * 1024 + tid;
    int v = (i < NN) ? deg[i] : 0;
    sh[tid] = v;
    __syncthreads();
    for (int d = 1; d < 1024; d <<= 1) {
        int t = (tid >= d) ? sh[tid - d] : 0;
        __syncthreads();
        sh[tid] += t;
        __syncthreads();
    }
    if (i < NN) off[i] = sh[tid] - v;          // block-local exclusive
    if (tid == 1023) bsum[blockIdx.x] = sh[1023];
}

__global__ __launch_bounds__(64) void scan2_kernel(
    const int* __restrict__ bsum, int* __restrict__ bbase, int nb)
{
    int lane = threadIdx.x;
    int v = (lane < nb) ? bsum[lane] : 0;
    int orig = v;
    for (int d = 1; d < 64; d <<= 1) {
        int t = __shfl_up(v, d);
        if (lane >= d) v += t;
    }
    bbase[lane] = v - orig;                    // exclusive
}

__global__ __launch_bounds__(1024) void scan3_kernel(
    int* __restrict__ off, const int* __restrict__ bbase,
    int* __restrict__ cursor)
{
    int i = blockIdx.x * 1024 + threadIdx.x;
    if (i < NN) {
        int o = off[i] + bbase[blockIdx.x];
        off[i] = o;
        cursor[i] = o;
        if (i == NN - 1) off[NN] = NE;
    }
}

__global__ __launch_bounds__(256) void scatter_kernel(
    const int* __restrict__ ei, int* __restrict__ cursor,
    int* __restrict__ sidx, int* __restrict__ sdst, int* __restrict__ ssrc)
{
    int e = blockIdx.x * 256 + threadIdx.x;
    if (e < NE) {
        int d = ei[NE + e];
        int p = atomicAdd(&cursor[d], 1);
        sidx[p] = e;
        sdst[p] = d;
        ssrc[p] = ei[e];
    }
}

// ---------------------------------------------------------------------------
// Pre-pack edge_attr into sorted-edge order, bf16, 16B/edge (5 vals + 3 zero).
// This IS the MFMA B-fragment for (ks=4, quad=0): k=128..135 = {ea0..ea4,0,0,0}.
// ---------------------------------------------------------------------------
__global__ __launch_bounds__(256) void ea_pack_kernel(
    const float* __restrict__ ea, const int* __restrict__ sidx,
    uint4* __restrict__ ea_pk)
{
    int p = blockIdx.x * 256 + threadIdx.x;
    if (p < NE) {
        const float* s = ea + (size_t)sidx[p] * 5;
        uint4 v;
        v.x = pack_bf16x2(s[0], s[1]);
        v.y = pack_bf16x2(s[2], s[3]);
        v.z = pack_bf16x2(s[4], 0.0f);
        v.w = 0u;
        ea_pk[p] = v;
    }
}

// ---------------------------------------------------------------------------
// Pre-pack MLP weights into MFMA A-fragment order (bf16).
// elem(ks, mt, lane, j) = W[k = ks*32 + (lane>>4)*8 + j][ch = mt*16 + (lane&15)]
// ---------------------------------------------------------------------------
__global__ __launch_bounds__(256) void pack_weights_kernel(
    const float* __restrict__ eW1, const float* __restrict__ eW2,
    const float* __restrict__ nW1, const float* __restrict__ nW2,
    const float* __restrict__ dlW1, const float* __restrict__ dlW2,
    short* __restrict__ eW1pk, short* __restrict__ eW2pk,
    short* __restrict__ nW1pk, short* __restrict__ nW2pk,
    short* __restrict__ dlW1pk, short* __restrict__ dlW2pk)
{
    int l = blockIdx.y;
    int t = blockIdx.x * 256 + threadIdx.x;
    if (t < 10240) {
        int j = t & 7, lane = (t >> 3) & 63, mt = (t >> 9) & 3, ks = t >> 11;
        int k  = ks * 32 + (lane >> 4) * 8 + j;
        int ch = mt * 16 + (lane & 15);
        float v = (k < EIN) ? eW1[(size_t)l * EIN * H + k * H + ch] : 0.0f;
        eW1pk[(size_t)l * 10240 + t] = (short)f2bf(v);
    } else if (t < 14336) {
        int t2 = t - 10240;
        int j = t2 & 7, lane = (t2 >> 3) & 63, mt = (t2 >> 9) & 3, ks = t2 >> 11;
        int k = ks * 32 + (lane >> 4) * 8 + j;
        int ch = mt * 16 + (lane & 15);
        eW2pk[(size_t)l * 4096 + t2] = (short)f2bf(eW2[(size_t)l * H * H + k * H + ch]);
    } else if (t < 22528) {
        int t3 = t - 14336;
        int j = t3 & 7, lane = (t3 >> 3) & 63, mt = (t3 >> 9) & 3, ks = t3 >> 11;
        int k = ks * 32 + (lane >> 4) * 8 + j;
        int ch = mt * 16 + (lane & 15);
        nW1pk[(size_t)l * 8192 + t3] = (short)f2bf(nW1[(size_t)l * NIN * H + k * H + ch]);
    } else if (t < 26624) {
        int t4 = t - 22528;
        int j = t4 & 7, lane = (t4 >> 3) & 63, mt = (t4 >> 9) & 3, ks = t4 >> 11;
        int k = ks * 32 + (lane >> 4) * 8 + j;
        int ch = mt * 16 + (lane & 15);
        nW2pk[(size_t)l * 4096 + t4] = (short)f2bf(nW2[(size_t)l * H * H + k * H + ch]);
    } else if (t < 30720) {
        if (l == 0) {
            int t5 = t - 26624;
            int j = t5 & 7, lane = (t5 >> 3) & 63, mt = (t5 >> 9) & 3, ks = t5 >> 11;
            int k = ks * 32 + (lane >> 4) * 8 + j;
            int ch = mt * 16 + (lane & 15);
            dlW1pk[t5] = (short)f2bf(dlW1[k * H + ch]);
        }
    } else if (t < 31744) {
        if (l == 0) {
            int t6 = t - 30720;
            int j = t6 & 7, lane = (t6 >> 3) & 63, ks = t6 >> 9;
            int k = ks * 32 + (lane >> 4) * 8 + j;
            int m = lane & 15;
            float v = (m < 6) ? dlW2[k * 6 + m] : 0.0f;
            dlW2pk[t6] = (short)f2bf(v);
        }
    }
}

// ---------------------------------------------------------------------------
// Encoder: h = LN(silu([x, gv[batch]] @ W1 + b1) @ W2 + b2); writes h (fp32)
// and h2 (bf16 mirror used by MFMA B-fragment gathers).
// ---------------------------------------------------------------------------
__global__ __launch_bounds__(256) void encoder_kernel(
    const float* __restrict__ x, const int* __restrict__ batch,
    const float* __restrict__ case_p, const float* __restrict__ bc_p,
    const float* __restrict__ W1, const float* __restrict__ b1,
    const float* __restrict__ W2, const float* __restrict__ b2,
    const float* __restrict__ g, const float* __restrict__ be,
    float* __restrict__ h, unsigned int* __restrict__ h2)
{
    __shared__ float in_sh[64 * 17];
    __shared__ float m1_sh[64 * 65];
    __shared__ float red_sh[2 * 4 * 64];
    const int lane = threadIdx.x & 63;
    const int w    = threadIdx.x >> 6;
    const int wb   = __builtin_amdgcn_readfirstlane(w * 16);
    const int n0   = blockIdx.x * 64;

    for (int i = 0; i < 16; ++i) {
        int slot = w * 16 + i;
        int n = n0 + slot;
        if (n < NN && lane < 16) {
            float v;
            if (lane < 8) v = x[n * 8 + lane];
            else {
                int b = batch[n];
                v = (lane < 12) ? case_p[b * 4 + (lane - 8)]
                                : bc_p[b * 4 + (lane - 12)];
            }
            in_sh[slot * 17 + lane] = v;
        }
    }
    __syncthreads();

    float acc[16];
#pragma unroll
    for (int c = 0; c < 16; ++c) acc[c] = b1[wb + c];
    for (int k = 0; k < 16; ++k) {
        float a = in_sh[lane * 17 + k];
        const float4* wr = (const float4*)(W1 + k * 64 + wb);
        float4 w0 = wr[0], w1 = wr[1], w2 = wr[2], w3 = wr[3];
        acc[0]  = fmaf(a, w0.x, acc[0]);  acc[1]  = fmaf(a, w0.y, acc[1]);
        acc[2]  = fmaf(a, w0.z, acc[2]);  acc[3]  = fmaf(a, w0.w, acc[3]);
        acc[4]  = fmaf(a, w1.x, acc[4]);  acc[5]  = fmaf(a, w1.y, acc[5]);
        acc[6]  = fmaf(a, w1.z, acc[6]);  acc[7]  = fmaf(a, w1.w, acc[7]);
        acc[8]  = fmaf(a, w2.x, acc[8]);  acc[9]  = fmaf(a, w2.y, acc[9]);
        acc[10] = fmaf(a, w2.z, acc[10]); acc[11] = fmaf(a, w2.w, acc[11]);
        acc[12] = fmaf(a, w3.x, acc[12]); acc[13] = fmaf(a, w3.y, acc[13]);
        acc[14] = fmaf(a, w3.z, acc[14]); acc[15] = fmaf(a, w3.w, acc[15]);
    }
#pragma unroll
    for (int c = 0; c < 16; ++c) m1_sh[lane * 65 + wb + c] = silu_f(acc[c]);
    __syncthreads();

    float acc2[16];
#pragma unroll
    for (int c = 0; c < 16; ++c) acc2[c] = b2[wb + c];
    for (int k = 0; k < 64; ++k) {
        float a = m1_sh[lane * 65 + k];
        const float4* wr = (const float4*)(W2 + k * 64 + wb);
        float4 w0 = wr[0], w1 = wr[1], w2 = wr[2], w3 = wr[3];
        acc2[0]  = fmaf(a, w0.x, acc2[0]);  acc2[1]  = fmaf(a, w0.y, acc2[1]);
        acc2[2]  = fmaf(a, w0.z, acc2[2]);  acc2[3]  = fmaf(a, w0.w, acc2[3]);
        acc2[4]  = fmaf(a, w1.x, acc2[4]);  acc2[5]  = fmaf(a, w1.y, acc2[5]);
        acc2[6]  = fmaf(a, w1.z, acc2[6]);  acc2[7]  = fmaf(a, w1.w, acc2[7]);
        acc2[8]  = fmaf(a, w2.x, acc2[8]);  acc2[9]  = fmaf(a, w2.y, acc2[9]);
        acc2[10] = fmaf(a, w2.z, acc2[10]); acc2[11] = fmaf(a, w2.w, acc2[11]);
        acc2[12] = fmaf(a, w3.x, acc2[12]); acc2[13] = fmaf(a, w3.y, acc2[13]);
        acc2[14] = fmaf(a, w3.z, acc2[14]); acc2[15] = fmaf(a, w3.w, acc2[15]);
    }

    float s1 = 0.f, s2 = 0.f;
#pragma unroll
    for (int c = 0; c < 16; ++c) { s1 += acc2[c]; s2 += acc2[c] * acc2[c]; }
    red_sh[w * 64 + lane] = s1;
    red_sh[256 + w * 64 + lane] = s2;
    __syncthreads();
    float t1 = 0.f, t2 = 0.f;
#pragma unroll
    for (int j = 0; j < 4; ++j) {
        t1 += red_sh[j * 64 + lane];
        t2 += red_sh[256 + j * 64 + lane];
    }
    float mean = t1 * (1.0f / 64.0f);
    float var  = t2 * (1.0f / 64.0f) - mean * mean;
    float rstd = rsqrtf(var + 1e-5f);

    int n = n0 + lane;
    if (n < NN) {
        float vals[16];
#pragma unroll
        for (int c = 0; c < 16; ++c) {
            int ch = wb + c;
            vals[c] = (acc2[c] - mean) * rstd * g[ch] + be[ch];
            h[n * 64 + ch] = vals[c];
        }
        uint4 p0, p1;
        p0.x = pack_bf16x2(vals[0], vals[1]);   p0.y = pack_bf16x2(vals[2], vals[3]);
        p0.z = pack_bf16x2(vals[4], vals[5]);   p0.w = pack_bf16x2(vals[6], vals[7]);
        p1.x = pack_bf16x2(vals[8], vals[9]);   p1.y = pack_bf16x2(vals[10], vals[11]);
        p1.z = pack_bf16x2(vals[12], vals[13]); p1.w = pack_bf16x2(vals[14], vals[15]);
        *(uint4*)(h2 + (size_t)n * 32 + w * 8)     = p0;
        *(uint4*)(h2 + (size_t)n * 32 + w * 8 + 4) = p1;
    }
}

// ---------------------------------------------------------------------------
// Edge MLP, R21: R20's structure (4-window blocking, cross-window carry
// chain, dense sweep, DPP scan, fp32 atomics) with LDS cut 4x: the MID
// transpose is a SAME-WAVE write->read (no barrier), so one 2304 B MID per
// wave suffices -- write window j's epilogue, immediately read back its 2
// GEMM2 B-fragments into registers (bfr[4][2]), overwrite with j+1.
// LDS 36864 -> 9216 B/block: occupancy was LDS-capped at 4 blocks/CU (41%
// measured); now VGPR-limited (~96 live) -> ~5 blocks/CU. More waves fill
// the 37% idle issue slots (VALUBusy 63%, latency-stalled on gathers).
// ---------------------------------------------------------------------------
__global__ __launch_bounds__(256, 4) void edge_kernel(
    const unsigned int* __restrict__ h2,
    const int* __restrict__ sdst, const int* __restrict__ ssrc,
    const uint4* __restrict__ ea_pk,
    const short* __restrict__ W1pk, const float* __restrict__ b1,
    const short* __restrict__ W2pk, const float* __restrict__ b2,
    const float* __restrict__ g, const float* __restrict__ be,
    float* __restrict__ agg)
{
    __shared__ unsigned int lds[4 * 576];          // ONE MID per wave
    const int lane = threadIdx.x & 63;
    const int w    = threadIdx.x >> 6;
    const int quad = lane >> 4;
    const int l15  = lane & 15;
    const int rowb = lane & 48;                    // quad row base lane
    // bijective XCD swizzle for 6250 blocks: q=781, r=2 (m204)
    const int xcd  = blockIdx.x & 7;
    const int jj   = blockIdx.x >> 3;
    const int tile = (xcd < 2 ? xcd * 782 : 2 * 782 + (xcd - 2) * 781) + jj;
    const int e0   = tile * 256 + w * 64;          // wave's 64 edges, 4 windows
    unsigned int* MID = lds + w * 576;             // 16 rows x 36 words
    const bf16x8 zfrag = {0, 0, 0, 0, 0, 0, 0, 0};

    // indices + ea fragments for all 4 windows (fully unrolled -> registers)
    int pd[4], ps[4];
    uint4 pea[4];
#pragma unroll
    for (int j = 0; j < 4; ++j) {
        int ei = e0 + j * 16 + l15;
        pd[j] = sdst[ei];
        ps[j] = ssrc[ei];
        pea[j] = ea_pk[ei];
    }
    // direct B-fragment gathers for all 4 windows
    uint4 rA[4], rB[4], rC[4], rD[4];
#pragma unroll
    for (int j = 0; j < 4; ++j) {
        const unsigned int* dr = h2 + (size_t)pd[j] * 32 + quad * 4;
        const unsigned int* sr = h2 + (size_t)ps[j] * 32 + quad * 4;
        rA[j] = *(const uint4*)(dr);
        rB[j] = *(const uint4*)(dr + 16);
        rC[j] = *(const uint4*)(sr);
        rD[j] = *(const uint4*)(sr + 16);
    }

    // GEMM1: K=160; each A-fragment load feeds all 4 windows' MFMAs
    f32x4 acc1[4][4];
#pragma unroll
    for (int j = 0; j < 4; ++j)
#pragma unroll
        for (int mt = 0; mt < 4; ++mt) acc1[j][mt] = (f32x4){0, 0, 0, 0};

#define G1_STEP(KS, FR)                                                       \
    {                                                                         \
        const short* apk = W1pk + (size_t)((KS) * 4) * 512 + lane * 8;        \
        _Pragma("unroll")                                                     \
        for (int mt = 0; mt < 4; ++mt) {                                      \
            bf16x8 afrag = *(const bf16x8*)(apk + mt * 512);                  \
            _Pragma("unroll")                                                 \
            for (int j = 0; j < 4; ++j) {                                     \
                union { uint4 u; bf16x8 b; } bb; bb.u = FR[j];                \
                acc1[j][mt] = __builtin_amdgcn_mfma_f32_16x16x32_bf16(        \
                    afrag, bb.b, acc1[j][mt], 0, 0, 0);                       \
            }                                                                 \
        }                                                                     \
    }
    G1_STEP(0, rA)
    G1_STEP(1, rB)
    G1_STEP(2, rC)
    G1_STEP(3, rD)
#undef G1_STEP
    {   // ks=4: edge_attr fragment (quad0 only)
        const short* apk = W1pk + (size_t)(4 * 4) * 512 + lane * 8;
#pragma unroll
        for (int mt = 0; mt < 4; ++mt) {
            bf16x8 afrag = *(const bf16x8*)(apk + mt * 512);
#pragma unroll
            for (int j = 0; j < 4; ++j) {
                union { uint4 u; bf16x8 b; } bb; bb.u = pea[j];
                bf16x8 kf = (quad == 0) ? bb.b : zfrag;
                acc1[j][mt] = __builtin_amdgcn_mfma_f32_16x16x32_bf16(
                    afrag, kf, acc1[j][mt], 0, 0, 0);
            }
        }
    }

    // epilogue 1: bias + silu -> single MID; read back GEMM2 B-frags into
    // registers before the next window overwrites (same wave -> in-order
    // LDS, no barrier; compiler inserts lgkmcnt waits).
    bf16x8 bfr[4][2];
#pragma unroll
    for (int j = 0; j < 4; ++j) {
#pragma unroll
        for (int mt = 0; mt < 4; ++mt) {
            int ch0 = mt * 16 + quad * 4;
            float bb0 = b1[ch0 + 0], bb1v = b1[ch0 + 1];
            float bb2v = b1[ch0 + 2], bb3 = b1[ch0 + 3];
            uint2 pk;
            pk.x = pack_bf16x2(silu_f(acc1[j][mt][0] + bb0),
                               silu_f(acc1[j][mt][1] + bb1v));
            pk.y = pack_bf16x2(silu_f(acc1[j][mt][2] + bb2v),
                               silu_f(acc1[j][mt][3] + bb3));
            *(uint2*)(MID + l15 * 36 + mt * 8 + quad * 2) = pk;
        }
#pragma unroll
        for (int ks = 0; ks < 2; ++ks)
            bfr[j][ks] = *(const bf16x8*)(MID + l15 * 36 + ks * 16 + quad * 4);
    }

    // GEMM2: K=64; each W2 A-fragment load feeds all 4 windows' MFMAs
    f32x4 acc2[4][4];
#pragma unroll
    for (int j = 0; j < 4; ++j)
#pragma unroll
        for (int mt = 0; mt < 4; ++mt) acc2[j][mt] = (f32x4){0, 0, 0, 0};
#pragma unroll
    for (int ks = 0; ks < 2; ++ks) {
        const short* apk = W2pk + (size_t)(ks * 4) * 512 + lane * 8;
#pragma unroll
        for (int mt = 0; mt < 4; ++mt) {
            bf16x8 afrag = *(const bf16x8*)(apk + mt * 512);
#pragma unroll
            for (int j = 0; j < 4; ++j) {
                acc2[j][mt] = __builtin_amdgcn_mfma_f32_16x16x32_bf16(
                    afrag, bfr[j][ks], acc2[j][mt], 0, 0, 0);
            }
        }
    }

    // per-window: bias + LN (3-op form) + segmented scan + cross-window
    // carry + conditional atomic. prevv holds the previous window's
    // POST-CARRY scan values (lane 15 of each quad row = trailing total).
    float prevv[16];
#define FINISH(J)                                                             \
    {                                                                         \
        float vals[16];                                                       \
        float s1 = 0.f, s2 = 0.f;                                             \
        _Pragma("unroll")                                                     \
        for (int mt = 0; mt < 4; ++mt) {                                      \
            _Pragma("unroll")                                                 \
            for (int r = 0; r < 4; ++r) {                                     \
                int ch = mt * 16 + quad * 4 + r;                              \
                float vv = acc2[J][mt][r] + b2[ch];                           \
                vals[mt * 4 + r] = vv;                                        \
                s1 += vv; s2 += vv * vv;                                      \
            }                                                                 \
        }                                                                     \
        s1 += __shfl_xor(s1, 16); s1 += __shfl_xor(s1, 32);                   \
        s2 += __shfl_xor(s2, 16); s2 += __shfl_xor(s2, 32);                   \
        float mean = s1 * (1.0f / 64.0f);                                     \
        float var  = s2 * (1.0f / 64.0f) - mean * mean;                       \
        float rstd = rsqrtf(var + 1e-5f);                                     \
        _Pragma("unroll")                                                     \
        for (int mt = 0; mt < 4; ++mt) {                                      \
            _Pragma("unroll")                                                 \
            for (int r = 0; r < 4; ++r) {                                     \
                int ch = mt * 16 + quad * 4 + r;                              \
                float rg  = rstd * g[ch];                                     \
                float off = fmaf(-mean, rg, be[ch]);                          \
                vals[mt * 4 + r] = fmaf(vals[mt * 4 + r], rg, off);           \
            }                                                                 \
        }                                                                     \
        int d_l = pd[J];                                                      \
        {                                                                     \
            int d_up = dpp_i<0x111>(-1, d_l);                                 \
            float msk = (d_up == d_l) ? 1.0f : 0.0f;                          \
            _Pragma("unroll")                                                 \
            for (int c = 0; c < 16; ++c) {                                    \
                float vu = __int_as_float(                                    \
                    dpp_i<0x111>(0, __float_as_int(vals[c])));                \
                vals[c] = fmaf(vu, msk, vals[c]);                             \
            }                                                                 \
        }                                                                     \
        {                                                                     \
            int d_up = dpp_i<0x112>(-1, d_l);                                 \
            float msk = (d_up == d_l) ? 1.0f : 0.0f;                          \
            _Pragma("unroll")                                                 \
            for (int c = 0; c < 16; ++c) {                                    \
                float vu = __int_as_float(                                    \
                    dpp_i<0x112>(0, __float_as_int(vals[c])));                \
                vals[c] = fmaf(vu, msk, vals[c]);                             \
            }                                                                 \
        }                                                                     \
        {                                                                     \
            int d_up = dpp_i<0x114>(-1, d_l);                                 \
            float msk = (d_up == d_l) ? 1.0f : 0.0f;                          \
            _Pragma("unroll")                                                 \
            for (int c = 0; c < 16; ++c) {                                    \
                float vu = __int_as_float(                                    \
                    dpp_i<0x114>(0, __float_as_int(vals[c])));                \
                vals[c] = fmaf(vu, msk, vals[c]);                             \
            }                                                                 \
        }                                                                     \
        {                                                                     \
            int d_up = dpp_i<0x118>(-1, d_l);                                 \
            float msk = (d_up == d_l) ? 1.0f : 0.0f;                          \
            _Pragma("unroll")                                                 \
            for (int c = 0; c < 16; ++c) {                                    \
                float vu = __int_as_float(                                    \
                    dpp_i<0x118>(0, __float_as_int(vals[c])));                \
                vals[c] = fmaf(vu, msk, vals[c]);                             \
            }                                                                 \
        }                                                                     \
        if ((J) > 0) {  /* carry in from previous window's trailing segment */\
            int prevd = __shfl(pd[(J) > 0 ? (J) - 1 : 0], rowb | 15);         \
            float mk = (d_l == prevd) ? 1.0f : 0.0f;                          \
            _Pragma("unroll")                                                 \
            for (int c = 0; c < 16; ++c) {                                    \
                float cv = __shfl(prevv[c], rowb | 15);                       \
                vals[c] = fmaf(cv, mk, vals[c]);                              \
            }                                                                 \
        }                                                                     \
        _Pragma("unroll")                                                     \
        for (int c = 0; c < 16; ++c) prevv[c] = vals[c];                      \
        int nd = dpp_i<0x101>(-1, d_l);  /* lane i <- lane i+1; l15 -> -1 */  \
        if ((J) < 3) {  /* lookahead: suppress atomic if segment continues */ \
            int nx = __shfl(pd[(J) < 3 ? (J) + 1 : 3], rowb);                 \
            nd = (l15 == 15) ? nx : nd;                                       \
        }                                                                     \
        bool last = (nd != d_l);                                              \
        if (last) {                                                           \
            _Pragma("unroll")                                                 \
            for (int mt = 0; mt < 4; ++mt) {                                  \
                _Pragma("unroll")                                             \
                for (int r = 0; r < 4; ++r) {                                 \
                    int ch = mt * 16 + quad * 4 + r;                          \
                    atomicAdd(&agg[(size_t)d_l * 64 + ch], vals[mt * 4 + r]); \
                }                                                             \
            }                                                                 \
        }                                                                     \
    }
    FINISH(0)
    FINISH(1)
    FINISH(2)
    FINISH(3)
#undef FINISH
}

// ---------------------------------------------------------------------------
// Node MLP via MFMA + residual: h = h + LN(silu([h,agg]@W1+b1)@W2+b2)
// Direct global B-frag gathers (h2 uint4; agg float4 + cvt_pk).
// ---------------------------------------------------------------------------
__global__ __launch_bounds__(256, 6) void node_kernel(
    float* __restrict__ h, unsigned int* __restrict__ h2,
    const float* __restrict__ agg,
    const short* __restrict__ W1pk, const float* __restrict__ b1,
    const short* __restrict__ W2pk, const float* __restrict__ b2,
    const float* __restrict__ g, const float* __restrict__ be)
{
    __shared__ unsigned int lds[4 * 576];
    const int lane = threadIdx.x & 63;
    const int w    = threadIdx.x >> 6;
    const int quad = lane >> 4;
    const int l15  = lane & 15;
    const int n0   = blockIdx.x * 64 + w * 16;     // this wave's 16 nodes
    unsigned int* MID = lds + w * 576;             // 16 rows x 36 words

    int n_l = n0 + l15; if (n_l >= NN) n_l = NN - 1;   // tail clamp (discarded)

    // direct B-fragments: h2 channels [quad*8..+7] (ks0) / [32+quad*8..] (ks1)
    const unsigned int* nrow = h2 + (size_t)n_l * 32 + quad * 4;
    union { uint4 u; bf16x8 b; } bfA, bfB;
    bfA.u = *(const uint4*)(nrow);
    bfB.u = *(const uint4*)(nrow + 16);
    // agg channels [quad*8..+7] (ks2) / [32+quad*8..] (ks3), fp32 -> bf16
    const float* ap = agg + (size_t)n_l * 64 + quad * 8;
    float4 a0 = *(const float4*)(ap);
    float4 a1 = *(const float4*)(ap + 4);
    float4 a2 = *(const float4*)(ap + 32);
    float4 a3 = *(const float4*)(ap + 36);
    union { unsigned int u[4]; bf16x8 b; } bfC, bfD;
    bfC.u[0] = pack_bf16x2(a0.x, a0.y); bfC.u[1] = pack_bf16x2(a0.z, a0.w);
    bfC.u[2] = pack_bf16x2(a1.x, a1.y); bfC.u[3] = pack_bf16x2(a1.z, a1.w);
    bfD.u[0] = pack_bf16x2(a2.x, a2.y); bfD.u[1] = pack_bf16x2(a2.z, a2.w);
    bfD.u[2] = pack_bf16x2(a3.x, a3.y); bfD.u[3] = pack_bf16x2(a3.z, a3.w);

    // GEMM1: K=128 (4 ks)
    f32x4 acc1[4] = {{0,0,0,0},{0,0,0,0},{0,0,0,0},{0,0,0,0}};
#define G1_STEP(KS, BFRAG)                                                    \
    {                                                                         \
        const short* apk = W1pk + (size_t)((KS) * 4) * 512 + lane * 8;        \
        _Pragma("unroll")                                                     \
        for (int mt = 0; mt < 4; ++mt) {                                      \
            bf16x8 afrag = *(const bf16x8*)(apk + mt * 512);                  \
            acc1[mt] = __builtin_amdgcn_mfma_f32_16x16x32_bf16(               \
                afrag, BFRAG, acc1[mt], 0, 0, 0);                             \
        }                                                                     \
    }
    G1_STEP(0, bfA.b)
    G1_STEP(1, bfB.b)
    G1_STEP(2, bfC.b)
    G1_STEP(3, bfD.b)
#undef G1_STEP

#pragma unroll
    for (int mt = 0; mt < 4; ++mt) {
        int ch0 = mt * 16 + quad * 4;
        float v0 = silu_f(acc1[mt][0] + b1[ch0 + 0]);
        float v1 = silu_f(acc1[mt][1] + b1[ch0 + 1]);
        float v2 = silu_f(acc1[mt][2] + b1[ch0 + 2]);
        float v3 = silu_f(acc1[mt][3] + b1[ch0 + 3]);
        uint2 pk;
        pk.x = pack_bf16x2(v0, v1);
        pk.y = pack_bf16x2(v2, v3);
        *(uint2*)(MID + l15 * 36 + mt * 8 + quad * 2) = pk;
    }

    // GEMM2: K=64 (2 ks)
    f32x4 acc2[4] = {{0,0,0,0},{0,0,0,0},{0,0,0,0},{0,0,0,0}};
    const unsigned int* mrow = MID + l15 * 36;
    for (int ks = 0; ks < 2; ++ks) {
        bf16x8 bfrag = *(const bf16x8*)(mrow + ks * 16 + quad * 4);
        const short* apk = W2pk + (size_t)(ks * 4) * 512 + lane * 8;
#pragma unroll
        for (int mt = 0; mt < 4; ++mt) {
            bf16x8 afrag = *(const bf16x8*)(apk + mt * 512);
            acc2[mt] = __builtin_amdgcn_mfma_f32_16x16x32_bf16(
                afrag, bfrag, acc2[mt], 0, 0, 0);
        }
    }

    // bias + LN over the 64 channels of this lane's node
    float vals[16];
    float s1 = 0.f, s2 = 0.f;
#pragma unroll
    for (int mt = 0; mt < 4; ++mt) {
#pragma unroll
        for (int r = 0; r < 4; ++r) {
            int ch = mt * 16 + quad * 4 + r;
            float vv = acc2[mt][r] + b2[ch];
            vals[mt * 4 + r] = vv;
            s1 += vv; s2 += vv * vv;
        }
    }
    s1 += __shfl_xor(s1, 16); s1 += __shfl_xor(s1, 32);
    s2 += __shfl_xor(s2, 16); s2 += __shfl_xor(s2, 32);
    float mean = s1 * (1.0f / 64.0f);
    float var  = s2 * (1.0f / 64.0f) - mean * mean;
    float rstd = rsqrtf(var + 1e-5f);

    int n = n0 + l15;
    if (n < NN) {
#pragma unroll
        for (int mt = 0; mt < 4; ++mt) {
            int ch0 = mt * 16 + quad * 4;
            float4 hv = *(const float4*)(h + (size_t)n * 64 + ch0);
            float o0 = hv.x + (vals[mt*4+0] - mean) * rstd * g[ch0+0] + be[ch0+0];
            float o1 = hv.y + (vals[mt*4+1] - mean) * rstd * g[ch0+1] + be[ch0+1];
            float o2 = hv.z + (vals[mt*4+2] - mean) * rstd * g[ch0+2] + be[ch0+2];
            float o3 = hv.w + (vals[mt*4+3] - mean) * rstd * g[ch0+3] + be[ch0+3];
            float4 st = {o0, o1, o2, o3};
            *(float4*)(h + (size_t)n * 64 + ch0) = st;
            uint2 pk;
            pk.x = pack_bf16x2(o0, o1);
            pk.y = pack_bf16x2(o2, o3);
            *(uint2*)(h2 + (size_t)n * 32 + mt * 8 + quad * 2) = pk;
        }
    }
}

// ---------------------------------------------------------------------------
// Local decoder via MFMA: out_local = silu(h @ W1 + b1) @ W2 + b2 -> [NN, 6]
// ---------------------------------------------------------------------------
__global__ __launch_bounds__(256, 7) void dec_local_kernel(
    const unsigned int* __restrict__ h2,
    const short* __restrict__ W1pk, const float* __restrict__ b1,
    const short* __restrict__ W2pk, const float* __restrict__ b2,
    float* __restrict__ out)
{
    __shared__ unsigned int lds[4 * 576];
    const int lane = threadIdx.x & 63;
    const int w    = threadIdx.x >> 6;
    const int quad = lane >> 4;
    const int l15  = lane & 15;
    const int n0   = blockIdx.x * 64 + w * 16;
    unsigned int* MID = lds + w * 576;             // 16 rows x 36 words

    int n_l = n0 + l15; if (n_l >= NN) n_l = NN - 1;
    const unsigned int* nrow = h2 + (size_t)n_l * 32 + quad * 4;
    union { uint4 u; bf16x8 b; } bfA, bfB;
    bfA.u = *(const uint4*)(nrow);
    bfB.u = *(const uint4*)(nrow + 16);

    // GEMM1: K=64 (2 ks), M=64 (4 mt)
    f32x4 acc1[4] = {{0,0,0,0},{0,0,0,0},{0,0,0,0},{0,0,0,0}};
#define G1_STEP(KS, BFRAG)                                                    \
    {                                                                         \
        const short* apk = W1pk + (size_t)((KS) * 4) * 512 + lane * 8;        \
        _Pragma("unroll")                                                     \
        for (int mt = 0; mt < 4; ++mt) {                                      \
            bf16x8 afrag = *(const bf16x8*)(apk + mt * 512);                  \
            acc1[mt] = __builtin_amdgcn_mfma_f32_16x16x32_bf16(               \
                afrag, BFRAG, acc1[mt], 0, 0, 0);                             \
        }                                                                     \
    }
    G1_STEP(0, bfA.b)
    G1_STEP(1, bfB.b)
#undef G1_STEP

    // epilogue: bias + silu -> MID (bf16)
#pragma unroll
    for (int mt = 0; mt < 4; ++mt) {
        int ch0 = mt * 16 + quad * 4;
        float v0 = silu_f(acc1[mt][0] + b1[ch0 + 0]);
        float v1 = silu_f(acc1[mt][1] + b1[ch0 + 1]);
        float v2 = silu_f(acc1[mt][2] + b1[ch0 + 2]);
        float v3 = silu_f(acc1[mt][3] + b1[ch0 + 3]);
        uint2 pk;
        pk.x = pack_bf16x2(v0, v1);
        pk.y = pack_bf16x2(v2, v3);
        *(uint2*)(MID + l15 * 36 + mt * 8 + quad * 2) = pk;
    }

    // GEMM2: K=64 (2 ks), M=16 (out padded 6->16)
    f32x4 acc2 = {0, 0, 0, 0};
    const unsigned int* mrow = MID + l15 * 36;
    for (int ks = 0; ks < 2; ++ks) {
        bf16x8 bfrag = *(const bf16x8*)(mrow + ks * 16 + quad * 4);
        bf16x8 afrag = *(const bf16x8*)(W2pk + (size_t)ks * 512 + lane * 8);
        acc2 = __builtin_amdgcn_mfma_f32_16x16x32_bf16(afrag, bfrag, acc2, 0, 0, 0);
    }

    int n = n0 + l15;
    if (n < NN && quad < 2) {
#pragma unroll
        for (int r = 0; r < 4; ++r) {
            int ch = quad * 4 + r;
            if (ch < 6) out[(size_t)n * 6 + ch] = acc2[r] + b2[ch];
        }
    }
}

// ---------------------------------------------------------------------------
// Pooling: pooled[g][c] = sum_{batch[n]==g} h[n][c];  cnt[g] = count
// ---------------------------------------------------------------------------
__global__ __launch_bounds__(256) void pool_kernel(
    const float* __restrict__ h, const int* __restrict__ batch,
    float* __restrict__ pooled, float* __restrict__ cnt)
{
    const int c   = threadIdx.x & 63;
    const int rep = blockIdx.x * 4 + (threadIdx.x >> 6);   // 1024 reps
    float acc[NG] = {0.f, 0.f, 0.f, 0.f};
    float cl[NG]  = {0.f, 0.f, 0.f, 0.f};
    for (int n = rep; n < NN; n += 1024) {
        int b = batch[n];
        float v = h[n * 64 + c];
#pragma unroll
        for (int gph = 0; gph < NG; ++gph) {
            if (b == gph) { acc[gph] += v; cl[gph] += 1.0f; }
        }
    }
#pragma unroll
    for (int gph = 0; gph < NG; ++gph) {
        atomicAdd(&pooled[gph * 64 + c], acc[gph]);
        if (c == 0) atomicAdd(&cnt[gph], cl[gph]);
    }
}

// ---------------------------------------------------------------------------
// Global decoder: out_global = silu(mean_pool @ W1 + b1) @ W2 + b2 -> [4,4]
// ---------------------------------------------------------------------------
__global__ __launch_bounds__(256) void dec_global_kernel(
    const float* __restrict__ pooled, const float* __restrict__ cnt,
    const float* __restrict__ W1, const float* __restrict__ b1,
    const float* __restrict__ W2, const float* __restrict__ b2,
    float* __restrict__ out)
{
    __shared__ float mid_sh[4][32];
    const int lane = threadIdx.x & 63;
    const int gph  = threadIdx.x >> 6;
    float inv = 1.0f / fmaxf(cnt[gph], 1.0f);
    if (lane < 32) {
        float a = b1[lane];
        for (int k = 0; k < 64; ++k)
            a = fmaf(pooled[gph * 64 + k] * inv, W1[k * 32 + lane], a);
        mid_sh[gph][lane] = silu_f(a);
    }
    __syncthreads();
    if (lane < 4) {
        float o = b2[lane];
        for (int k = 0; k < 32; ++k)
            o = fmaf(mid_sh[gph][k], W2[k * 4 + lane], o);
        out[gph * 4 + lane] = o;
    }
}

// ---------------------------------------------------------------------------
extern "C" void kernel_launch(void* const* d_in, const int* in_sizes, int n_in,
                              void* d_out, int out_size, void* d_ws, size_t ws_size,
                              hipStream_t stream)
{
    const float* x      = (const float*)d_in[0];
    const int*   ei     = (const int*)  d_in[1];
    const float* ea     = (const float*)d_in[2];
    const int*   batch  = (const int*)  d_in[3];
    const float* case_p = (const float*)d_in[4];
    const float* bc_p   = (const float*)d_in[5];
    const float* enc_W1 = (const float*)d_in[6];
    const float* enc_b1 = (const float*)d_in[7];
    const float* enc_W2 = (const float*)d_in[8];
    const float* enc_b2 = (const float*)d_in[9];
    const float* enc_g  = (const float*)d_in[10];
    const float* enc_be = (const float*)d_in[11];
    const float* eW1    = (const float*)d_in[12];
    const float* eb1    = (const float*)d_in[13];
    const float* eW2    = (const float*)d_in[14];
    const float* eb2    = (const float*)d_in[15];
    const float* eg     = (const float*)d_in[16];
    const float* ebe    = (const float*)d_in[17];
    const float* nW1    = (const float*)d_in[18];
    const float* nb1    = (const float*)d_in[19];
    const float* nW2    = (const float*)d_in[20];
    const float* nb2    = (const float*)d_in[21];
    const float* ng     = (const float*)d_in[22];
    const float* nbe    = (const float*)d_in[23];
    const float* dlW1   = (const float*)d_in[24];
    const float* dlb1   = (const float*)d_in[25];
    const float* dlW2   = (const float*)d_in[26];
    const float* dlb2   = (const float*)d_in[27];
    const float* dgW1   = (const float*)d_in[28];
    const float* dgb1   = (const float*)d_in[29];
    const float* dgW2   = (const float*)d_in[30];
    const float* dgb2   = (const float*)d_in[31];

    float* out = (float*)d_out;

    char* ws = (char*)d_ws;
    size_t off_b = 0;
    auto alloc = [&](size_t bytes) {
        void* p = ws + off_b;
        off_b = (off_b + bytes + 255) & ~(size_t)255;
        return p;
    };
    const size_t hBytes = (size_t)NN * H * sizeof(float);     // 12.8 MB
    float*        h      = (float*)alloc(hBytes);
    float*        agg    = (float*)alloc(hBytes);
    unsigned int* h2     = (unsigned int*)alloc((size_t)NN * 32 * 4);  // bf16 mirror
    float*        pooled = (float*)alloc(256 * sizeof(float));
    float*        cnt    = (float*)alloc(4 * sizeof(float));
    int*          deg    = (int*)alloc((NN + 1) * sizeof(int));
    int*          offs   = (int*)alloc((NN + 1) * sizeof(int));
    int*          cursor = (int*)alloc((NN + 1) * sizeof(int));
    int*          bsum   = (int*)alloc(64 * sizeof(int));
    int*          bbase  = (int*)alloc(64 * sizeof(int));
    int*          sidx   = (int*)alloc((size_t)NE * sizeof(int));
    int*          sdst   = (int*)alloc((size_t)NE * sizeof(int));
    int*          ssrc   = (int*)alloc((size_t)NE * sizeof(int));
    uint4*        ea_pk  = (uint4*)alloc((size_t)NE * sizeof(uint4));  // 25.6 MB
    short*        eW1pk  = (short*)alloc((size_t)NL * 10240 * sizeof(short));
    short*        eW2pk  = (short*)alloc((size_t)NL * 4096 * sizeof(short));
    short*        nW1pk  = (short*)alloc((size_t)NL * 8192 * sizeof(short));
    short*        nW2pk  = (short*)alloc((size_t)NL * 4096 * sizeof(short));
    short*        dlW1pk = (short*)alloc(4096 * sizeof(short));
    short*        dlW2pk = (short*)alloc(1024 * sizeof(short));

    hipMemsetAsync(pooled, 0, (256 + 4 + 64) * sizeof(float), stream);
    hipMemsetAsync(deg, 0, (NN + 1) * sizeof(int), stream);

    const int NB = (NN + 1023) / 1024;   // 49
    degree_kernel<<<(NE + 255) / 256, 256, 0, stream>>>(ei, deg);
    scan1_kernel<<<NB, 1024, 0, stream>>>(deg, offs, bsum);
    scan2_kernel<<<1, 64, 0, stream>>>(bsum, bbase, NB);
    scan3_kernel<<<NB, 1024, 0, stream>>>(offs, bbase, cursor);
    scatter_kernel<<<(NE + 255) / 256, 256, 0, stream>>>(ei, cursor, sidx, sdst, ssrc);
    ea_pack_kernel<<<(NE + 255) / 256, 256, 0, stream>>>(ea, sidx, ea_pk);
    pack_weights_kernel<<<dim3(124, NL), 256, 0, stream>>>(
        eW1, eW2, nW1, nW2, dlW1, dlW2,
        eW1pk, eW2pk, nW1pk, nW2pk, dlW1pk, dlW2pk);

    const int nodeBlocks = (NN + 63) / 64;    // 782
    encoder_kernel<<<nodeBlocks, 256, 0, stream>>>(
        x, batch, case_p, bc_p, enc_W1, enc_b1, enc_W2, enc_b2, enc_g, enc_be,
        h, h2);

    const int edgeBlocks = NE / 256;          // 6250 (4 windows per wave)
    for (int l = 0; l < NL; ++l) {
        hipMemsetAsync(agg, 0, hBytes, stream);
        edge_kernel<<<edgeBlocks, 256, 0, stream>>>(
            h2, sdst, ssrc, ea_pk,
            eW1pk + (size_t)l * 10240, eb1 + l * H,
            eW2pk + (size_t)l * 4096,  eb2 + l * H,
            eg + l * H, ebe + l * H, agg);
        node_kernel<<<nodeBlocks, 256, 0, stream>>>(
            h, h2, agg,
            nW1pk + (size_t)l * 8192, nb1 + l * H,
            nW2pk + (size_t)l * 4096, nb2 + l * H,
            ng + l * H, nbe + l * H);
    }

    dec_local_kernel<<<nodeBlocks, 256, 0, stream>>>(
        h2, dlW1pk, dlb1, dlW2pk, dlb2, out);
    pool_kernel<<<256, 256, 0, stream>>>(h, batch, pooled, cnt);
    dec_global_kernel<<<1, 256, 0, stream>>>(pooled, cnt, dgW1, dgb1, dgW2, dgb2,
                                             out + (size_t)NN * 6);
}

// Round 11
// 1387.403 us; speedup vs baseline: 1.0353x; 1.0353x over previous
//
#include <hip/hip_runtime.h>
#include <cmath>

// Problem constants (from reference)
constexpr int NN = 50000;      // nodes
constexpr int NE = 1600000;    // edges
constexpr int H  = 64;         // hidden
constexpr int NL = 5;          // layers
constexpr int NG = 4;          // graphs
constexpr int EIN = 2 * H + 5; // 133
constexpr int NIN = 2 * H;     // 128

typedef short bf16x8 __attribute__((ext_vector_type(8)));
typedef float f32x4  __attribute__((ext_vector_type(4)));

__device__ __forceinline__ float silu_f(float x) {
    return x / (1.0f + __expf(-x));
}

// round-to-nearest-even fp32 -> bf16 bits (scalar, cold paths)
__device__ __forceinline__ unsigned int f2bf(float f) {
    unsigned int u = __float_as_uint(f);
    u += 0x7fffu + ((u >> 16) & 1u);
    return u >> 16;
}
// hot-path pack: single HW instruction (RNE), x -> low half, y -> high half
__device__ __forceinline__ unsigned int pack_bf16x2(float x, float y) {
    unsigned int r;
    asm("v_cvt_pk_bf16_f32 %0, %1, %2" : "=v"(r) : "v"(x), "v"(y));
    return r;
}

// DPP lane-shift within 16-lane rows (VALU pipe, not ds_bpermute).
// row_shr:N = 0x110|N (lane i <- lane i-N within row); row_shl:1 = 0x101.
// bound_ctrl=false: out-of-row lanes keep `old`.
template <int CTRL>
__device__ __forceinline__ int dpp_i(int old, int v) {
    return __builtin_amdgcn_update_dpp(old, v, CTRL, 0xF, 0xF, false);
}

// ---------------------------------------------------------------------------
// Counting sort of edges by dst
// ---------------------------------------------------------------------------
__global__ __launch_bounds__(256) void degree_kernel(
    const int* __restrict__ ei, int* __restrict__ deg)
{
    int e = blockIdx.x * 256 + threadIdx.x;
    if (e < NE) atomicAdd(&deg[ei[NE + e]], 1);
}

__global__ __launch_bounds__(1024) void scan1_kernel(
    const int* __restrict__ deg, int* __restrict__ off, int* __restrict__ bsum)
{
    __shared__ int sh[1024];
    const int tid = threadIdx.x;
    int i = blockIdx.x * 1024 + tid;
    int v = (i < NN) ? deg[i] : 0;
    sh[tid] = v;
    __syncthreads();
    for (int d = 1; d < 1024; d <<= 1) {
        int t = (tid >= d) ? sh[tid - d] : 0;
        __syncthreads();
        sh[tid] += t;
        __syncthreads();
    }
    if (i < NN) off[i] = sh[tid] - v;          // block-local exclusive
    if (tid == 1023) bsum[blockIdx.x] = sh[1023];
}

__global__ __launch_bounds__(64) void scan2_kernel(
    const int* __restrict__ bsum, int* __restrict__ bbase, int nb)
{
    int lane = threadIdx.x;
    int v = (lane < nb) ? bsum[lane] : 0;
    int orig = v;
    for (int d = 1; d < 64; d <<= 1) {
        int t = __shfl_up(v, d);
        if (lane >= d) v += t;
    }
    bbase[lane] = v - orig;                    // exclusive
}

__global__ __launch_bounds__(1024) void scan3_kernel(
    int* __restrict__ off, const int* __restrict__ bbase,
    int* __restrict__ cursor)
{
    int i = blockIdx.x * 1024 + threadIdx.x;
    if (i < NN) {
        int o = off[i] + bbase[blockIdx.x];
        off[i] = o;
        cursor[i] = o;
        if (i == NN - 1) off[NN] = NE;
    }
}

__global__ __launch_bounds__(256) void scatter_kernel(
    const int* __restrict__ ei, int* __restrict__ cursor,
    int* __restrict__ sidx, int* __restrict__ sdst, int* __restrict__ ssrc)
{
    int e = blockIdx.x * 256 + threadIdx.x;
    if (e < NE) {
        int d = ei[NE + e];
        int p = atomicAdd(&cursor[d], 1);
        sidx[p] = e;
        sdst[p] = d;
        ssrc[p] = ei[e];
    }
}

// ---------------------------------------------------------------------------
// Pre-pack edge_attr into sorted-edge order, bf16, 16B/edge (5 vals + 3 zero).
// This IS the MFMA B-fragment for (ks=4, quad=0): k=128..135 = {ea0..ea4,0,0,0}.
// ---------------------------------------------------------------------------
__global__ __launch_bounds__(256) void ea_pack_kernel(
    const float* __restrict__ ea, const int* __restrict__ sidx,
    uint4* __restrict__ ea_pk)
{
    int p = blockIdx.x * 256 + threadIdx.x;
    if (p < NE) {
        const float* s = ea + (size_t)sidx[p] * 5;
        uint4 v;
        v.x = pack_bf16x2(s[0], s[1]);
        v.y = pack_bf16x2(s[2], s[3]);
        v.z = pack_bf16x2(s[4], 0.0f);
        v.w = 0u;
        ea_pk[p] = v;
    }
}

// ---------------------------------------------------------------------------
// Pre-pack MLP weights into MFMA A-fragment order (bf16).
// elem(ks, mt, lane, j) = W[k = ks*32 + (lane>>4)*8 + j][ch = mt*16 + (lane&15)]
// ---------------------------------------------------------------------------
__global__ __launch_bounds__(256) void pack_weights_kernel(
    const float* __restrict__ eW1, const float* __restrict__ eW2,
    const float* __restrict__ nW1, const float* __restrict__ nW2,
    const float* __restrict__ dlW1, const float* __restrict__ dlW2,
    short* __restrict__ eW1pk, short* __restrict__ eW2pk,
    short* __restrict__ nW1pk, short* __restrict__ nW2pk,
    short* __restrict__ dlW1pk, short* __restrict__ dlW2pk)
{
    int l = blockIdx.y;
    int t = blockIdx.x * 256 + threadIdx.x;
    if (t < 10240) {
        int j = t & 7, lane = (t >> 3) & 63, mt = (t >> 9) & 3, ks = t >> 11;
        int k  = ks * 32 + (lane >> 4) * 8 + j;
        int ch = mt * 16 + (lane & 15);
        float v = (k < EIN) ? eW1[(size_t)l * EIN * H + k * H + ch] : 0.0f;
        eW1pk[(size_t)l * 10240 + t] = (short)f2bf(v);
    } else if (t < 14336) {
        int t2 = t - 10240;
        int j = t2 & 7, lane = (t2 >> 3) & 63, mt = (t2 >> 9) & 3, ks = t2 >> 11;
        int k = ks * 32 + (lane >> 4) * 8 + j;
        int ch = mt * 16 + (lane & 15);
        eW2pk[(size_t)l * 4096 + t2] = (short)f2bf(eW2[(size_t)l * H * H + k * H + ch]);
    } else if (t < 22528) {
        int t3 = t - 14336;
        int j = t3 & 7, lane = (t3 >> 3) & 63, mt = (t3 >> 9) & 3, ks = t3 >> 11;
        int k = ks * 32 + (lane >> 4) * 8 + j;
        int ch = mt * 16 + (lane & 15);
        nW1pk[(size_t)l * 8192 + t3] = (short)f2bf(nW1[(size_t)l * NIN * H + k * H + ch]);
    } else if (t < 26624) {
        int t4 = t - 22528;
        int j = t4 & 7, lane = (t4 >> 3) & 63, mt = (t4 >> 9) & 3, ks = t4 >> 11;
        int k = ks * 32 + (lane >> 4) * 8 + j;
        int ch = mt * 16 + (lane & 15);
        nW2pk[(size_t)l * 4096 + t4] = (short)f2bf(nW2[(size_t)l * H * H + k * H + ch]);
    } else if (t < 30720) {
        if (l == 0) {
            int t5 = t - 26624;
            int j = t5 & 7, lane = (t5 >> 3) & 63, mt = (t5 >> 9) & 3, ks = t5 >> 11;
            int k = ks * 32 + (lane >> 4) * 8 + j;
            int ch = mt * 16 + (lane & 15);
            dlW1pk[t5] = (short)f2bf(dlW1[k * H + ch]);
        }
    } else if (t < 31744) {
        if (l == 0) {
            int t6 = t - 30720;
            int j = t6 & 7, lane = (t6 >> 3) & 63, ks = t6 >> 9;
            int k = ks * 32 + (lane >> 4) * 8 + j;
            int m = lane & 15;
            float v = (m < 6) ? dlW2[k * 6 + m] : 0.0f;
            dlW2pk[t6] = (short)f2bf(v);
        }
    }
}

// ---------------------------------------------------------------------------
// Encoder: h = LN(silu([x, gv[batch]] @ W1 + b1) @ W2 + b2); writes h (fp32)
// and h2 (bf16 mirror used by MFMA B-fragment gathers).
// ---------------------------------------------------------------------------
__global__ __launch_bounds__(256) void encoder_kernel(
    const float* __restrict__ x, const int* __restrict__ batch,
    const float* __restrict__ case_p, const float* __restrict__ bc_p,
    const float* __restrict__ W1, const float* __restrict__ b1,
    const float* __restrict__ W2, const float* __restrict__ b2,
    const float* __restrict__ g, const float* __restrict__ be,
    float* __restrict__ h, unsigned int* __restrict__ h2)
{
    __shared__ float in_sh[64 * 17];
    __shared__ float m1_sh[64 * 65];
    __shared__ float red_sh[2 * 4 * 64];
    const int lane = threadIdx.x & 63;
    const int w    = threadIdx.x >> 6;
    const int wb   = __builtin_amdgcn_readfirstlane(w * 16);
    const int n0   = blockIdx.x * 64;

    for (int i = 0; i < 16; ++i) {
        int slot = w * 16 + i;
        int n = n0 + slot;
        if (n < NN && lane < 16) {
            float v;
            if (lane < 8) v = x[n * 8 + lane];
            else {
                int b = batch[n];
                v = (lane < 12) ? case_p[b * 4 + (lane - 8)]
                                : bc_p[b * 4 + (lane - 12)];
            }
            in_sh[slot * 17 + lane] = v;
        }
    }
    __syncthreads();

    float acc[16];
#pragma unroll
    for (int c = 0; c < 16; ++c) acc[c] = b1[wb + c];
    for (int k = 0; k < 16; ++k) {
        float a = in_sh[lane * 17 + k];
        const float4* wr = (const float4*)(W1 + k * 64 + wb);
        float4 w0 = wr[0], w1 = wr[1], w2 = wr[2], w3 = wr[3];
        acc[0]  = fmaf(a, w0.x, acc[0]);  acc[1]  = fmaf(a, w0.y, acc[1]);
        acc[2]  = fmaf(a, w0.z, acc[2]);  acc[3]  = fmaf(a, w0.w, acc[3]);
        acc[4]  = fmaf(a, w1.x, acc[4]);  acc[5]  = fmaf(a, w1.y, acc[5]);
        acc[6]  = fmaf(a, w1.z, acc[6]);  acc[7]  = fmaf(a, w1.w, acc[7]);
        acc[8]  = fmaf(a, w2.x, acc[8]);  acc[9]  = fmaf(a, w2.y, acc[9]);
        acc[10] = fmaf(a, w2.z, acc[10]); acc[11] = fmaf(a, w2.w, acc[11]);
        acc[12] = fmaf(a, w3.x, acc[12]); acc[13] = fmaf(a, w3.y, acc[13]);
        acc[14] = fmaf(a, w3.z, acc[14]); acc[15] = fmaf(a, w3.w, acc[15]);
    }
#pragma unroll
    for (int c = 0; c < 16; ++c) m1_sh[lane * 65 + wb + c] = silu_f(acc[c]);
    __syncthreads();

    float acc2[16];
#pragma unroll
    for (int c = 0; c < 16; ++c) acc2[c] = b2[wb + c];
    for (int k = 0; k < 64; ++k) {
        float a = m1_sh[lane * 65 + k];
        const float4* wr = (const float4*)(W2 + k * 64 + wb);
        float4 w0 = wr[0], w1 = wr[1], w2 = wr[2], w3 = wr[3];
        acc2[0]  = fmaf(a, w0.x, acc2[0]);  acc2[1]  = fmaf(a, w0.y, acc2[1]);
        acc2[2]  = fmaf(a, w0.z, acc2[2]);  acc2[3]  = fmaf(a, w0.w, acc2[3]);
        acc2[4]  = fmaf(a, w1.x, acc2[4]);  acc2[5]  = fmaf(a, w1.y, acc2[5]);
        acc2[6]  = fmaf(a, w1.z, acc2[6]);  acc2[7]  = fmaf(a, w1.w, acc2[7]);
        acc2[8]  = fmaf(a, w2.x, acc2[8]);  acc2[9]  = fmaf(a, w2.y, acc2[9]);
        acc2[10] = fmaf(a, w2.z, acc2[10]); acc2[11] = fmaf(a, w2.w, acc2[11]);
        acc2[12] = fmaf(a, w3.x, acc2[12]); acc2[13] = fmaf(a, w3.y, acc2[13]);
        acc2[14] = fmaf(a, w3.z, acc2[14]); acc2[15] = fmaf(a, w3.w, acc2[15]);
    }

    float s1 = 0.f, s2 = 0.f;
#pragma unroll
    for (int c = 0; c < 16; ++c) { s1 += acc2[c]; s2 += acc2[c] * acc2[c]; }
    red_sh[w * 64 + lane] = s1;
    red_sh[256 + w * 64 + lane] = s2;
    __syncthreads();
    float t1 = 0.f, t2 = 0.f;
#pragma unroll
    for (int j = 0; j < 4; ++j) {
        t1 += red_sh[j * 64 + lane];
        t2 += red_sh[256 + j * 64 + lane];
    }
    float mean = t1 * (1.0f / 64.0f);
    float var  = t2 * (1.0f / 64.0f) - mean * mean;
    float rstd = rsqrtf(var + 1e-5f);

    int n = n0 + lane;
    if (n < NN) {
        float vals[16];
#pragma unroll
        for (int c = 0; c < 16; ++c) {
            int ch = wb + c;
            vals[c] = (acc2[c] - mean) * rstd * g[ch] + be[ch];
            h[n * 64 + ch] = vals[c];
        }
        uint4 p0, p1;
        p0.x = pack_bf16x2(vals[0], vals[1]);   p0.y = pack_bf16x2(vals[2], vals[3]);
        p0.z = pack_bf16x2(vals[4], vals[5]);   p0.w = pack_bf16x2(vals[6], vals[7]);
        p1.x = pack_bf16x2(vals[8], vals[9]);   p1.y = pack_bf16x2(vals[10], vals[11]);
        p1.z = pack_bf16x2(vals[12], vals[13]); p1.w = pack_bf16x2(vals[14], vals[15]);
        *(uint4*)(h2 + (size_t)n * 32 + w * 8)     = p0;
        *(uint4*)(h2 + (size_t)n * 32 + w * 8 + 4) = p1;
    }
}

// ---------------------------------------------------------------------------
// Edge MLP, R22 (= R20 exact revert, the session champion at 186 us):
// 4-window blocking (weights/bias amortized 4x), cross-window carry chain
// (atomic rounds ~3/wave), dense dispatch-order sweep (atomic L2
// residency), DPP segmented scan, fp32 atomics, direct B-frag gathers.
// R21's single-MID/LDS-thinning variant regressed (occupancy is NOT
// resource-capped: 41% at both 36.9KB and 9.2KB LDS) -- reverted.
// ---------------------------------------------------------------------------
__global__ __launch_bounds__(256, 4) void edge_kernel(
    const unsigned int* __restrict__ h2,
    const int* __restrict__ sdst, const int* __restrict__ ssrc,
    const uint4* __restrict__ ea_pk,
    const short* __restrict__ W1pk, const float* __restrict__ b1,
    const short* __restrict__ W2pk, const float* __restrict__ b2,
    const float* __restrict__ g, const float* __restrict__ be,
    float* __restrict__ agg)
{
    __shared__ unsigned int lds[4 * 2304];         // per wave: 4 MIDs x 576
    const int lane = threadIdx.x & 63;
    const int w    = threadIdx.x >> 6;
    const int quad = lane >> 4;
    const int l15  = lane & 15;
    const int rowb = lane & 48;                    // quad row base lane
    // bijective XCD swizzle for 6250 blocks: q=781, r=2 (m204)
    const int xcd  = blockIdx.x & 7;
    const int jj   = blockIdx.x >> 3;
    const int tile = (xcd < 2 ? xcd * 782 : 2 * 782 + (xcd - 2) * 781) + jj;
    const int e0   = tile * 256 + w * 64;          // wave's 64 edges, 4 windows
    unsigned int* MIDW = lds + w * 2304;           // 4 x (16 rows x 36 words)
    const bf16x8 zfrag = {0, 0, 0, 0, 0, 0, 0, 0};

    // indices + ea fragments for all 4 windows (fully unrolled -> registers)
    int pd[4], ps[4];
    uint4 pea[4];
#pragma unroll
    for (int j = 0; j < 4; ++j) {
        int ei = e0 + j * 16 + l15;
        pd[j] = sdst[ei];
        ps[j] = ssrc[ei];
        pea[j] = ea_pk[ei];
    }
    // direct B-fragment gathers for all 4 windows
    uint4 rA[4], rB[4], rC[4], rD[4];
#pragma unroll
    for (int j = 0; j < 4; ++j) {
        const unsigned int* dr = h2 + (size_t)pd[j] * 32 + quad * 4;
        const unsigned int* sr = h2 + (size_t)ps[j] * 32 + quad * 4;
        rA[j] = *(const uint4*)(dr);
        rB[j] = *(const uint4*)(dr + 16);
        rC[j] = *(const uint4*)(sr);
        rD[j] = *(const uint4*)(sr + 16);
    }

    // GEMM1: K=160; each A-fragment load feeds all 4 windows' MFMAs
    f32x4 acc1[4][4];
#pragma unroll
    for (int j = 0; j < 4; ++j)
#pragma unroll
        for (int mt = 0; mt < 4; ++mt) acc1[j][mt] = (f32x4){0, 0, 0, 0};

#define G1_STEP(KS, FR)                                                       \
    {                                                                         \
        const short* apk = W1pk + (size_t)((KS) * 4) * 512 + lane * 8;        \
        _Pragma("unroll")                                                     \
        for (int mt = 0; mt < 4; ++mt) {                                      \
            bf16x8 afrag = *(const bf16x8*)(apk + mt * 512);                  \
            _Pragma("unroll")                                                 \
            for (int j = 0; j < 4; ++j) {                                     \
                union { uint4 u; bf16x8 b; } bb; bb.u = FR[j];                \
                acc1[j][mt] = __builtin_amdgcn_mfma_f32_16x16x32_bf16(        \
                    afrag, bb.b, acc1[j][mt], 0, 0, 0);                       \
            }                                                                 \
        }                                                                     \
    }
    G1_STEP(0, rA)
    G1_STEP(1, rB)
    G1_STEP(2, rC)
    G1_STEP(3, rD)
#undef G1_STEP
    {   // ks=4: edge_attr fragment (quad0 only)
        const short* apk = W1pk + (size_t)(4 * 4) * 512 + lane * 8;
#pragma unroll
        for (int mt = 0; mt < 4; ++mt) {
            bf16x8 afrag = *(const bf16x8*)(apk + mt * 512);
#pragma unroll
            for (int j = 0; j < 4; ++j) {
                union { uint4 u; bf16x8 b; } bb; bb.u = pea[j];
                bf16x8 kf = (quad == 0) ? bb.b : zfrag;
                acc1[j][mt] = __builtin_amdgcn_mfma_f32_16x16x32_bf16(
                    afrag, kf, acc1[j][mt], 0, 0, 0);
            }
        }
    }

    // epilogue 1: bias + silu -> MID[j] (bias loads shared across windows)
#pragma unroll
    for (int mt = 0; mt < 4; ++mt) {
        int ch0 = mt * 16 + quad * 4;
        float bb0 = b1[ch0 + 0], bb1v = b1[ch0 + 1];
        float bb2v = b1[ch0 + 2], bb3 = b1[ch0 + 3];
#pragma unroll
        for (int j = 0; j < 4; ++j) {
            uint2 pk;
            pk.x = pack_bf16x2(silu_f(acc1[j][mt][0] + bb0),
                               silu_f(acc1[j][mt][1] + bb1v));
            pk.y = pack_bf16x2(silu_f(acc1[j][mt][2] + bb2v),
                               silu_f(acc1[j][mt][3] + bb3));
            *(uint2*)(MIDW + j * 576 + l15 * 36 + mt * 8 + quad * 2) = pk;
        }
    }

    // GEMM2: K=64; each W2 A-fragment load feeds all 4 windows' MFMAs
    f32x4 acc2[4][4];
#pragma unroll
    for (int j = 0; j < 4; ++j)
#pragma unroll
        for (int mt = 0; mt < 4; ++mt) acc2[j][mt] = (f32x4){0, 0, 0, 0};
#pragma unroll
    for (int ks = 0; ks < 2; ++ks) {
        bf16x8 bfr[4];
#pragma unroll
        for (int j = 0; j < 4; ++j)
            bfr[j] = *(const bf16x8*)(MIDW + j * 576 + l15 * 36 +
                                      ks * 16 + quad * 4);
        const short* apk = W2pk + (size_t)(ks * 4) * 512 + lane * 8;
#pragma unroll
        for (int mt = 0; mt < 4; ++mt) {
            bf16x8 afrag = *(const bf16x8*)(apk + mt * 512);
#pragma unroll
            for (int j = 0; j < 4; ++j) {
                acc2[j][mt] = __builtin_amdgcn_mfma_f32_16x16x32_bf16(
                    afrag, bfr[j], acc2[j][mt], 0, 0, 0);
            }
        }
    }

    // per-window: bias + LN (3-op form) + segmented scan + cross-window
    // carry + conditional atomic. prevv holds the previous window's
    // POST-CARRY scan values (lane 15 of each quad row = trailing total).
    float prevv[16];
#define FINISH(J)                                                             \
    {                                                                         \
        float vals[16];                                                       \
        float s1 = 0.f, s2 = 0.f;                                             \
        _Pragma("unroll")                                                     \
        for (int mt = 0; mt < 4; ++mt) {                                      \
            _Pragma("unroll")                                                 \
            for (int r = 0; r < 4; ++r) {                                     \
                int ch = mt * 16 + quad * 4 + r;                              \
                float vv = acc2[J][mt][r] + b2[ch];                           \
                vals[mt * 4 + r] = vv;                                        \
                s1 += vv; s2 += vv * vv;                                      \
            }                                                                 \
        }                                                                     \
        s1 += __shfl_xor(s1, 16); s1 += __shfl_xor(s1, 32);                   \
        s2 += __shfl_xor(s2, 16); s2 += __shfl_xor(s2, 32);                   \
        float mean = s1 * (1.0f / 64.0f);                                     \
        float var  = s2 * (1.0f / 64.0f) - mean * mean;                       \
        float rstd = rsqrtf(var + 1e-5f);                                     \
        _Pragma("unroll")                                                     \
        for (int mt = 0; mt < 4; ++mt) {                                      \
            _Pragma("unroll")                                                 \
            for (int r = 0; r < 4; ++r) {                                     \
                int ch = mt * 16 + quad * 4 + r;                              \
                float rg  = rstd * g[ch];                                     \
                float off = fmaf(-mean, rg, be[ch]);                          \
                vals[mt * 4 + r] = fmaf(vals[mt * 4 + r], rg, off);           \
            }                                                                 \
        }                                                                     \
        int d_l = pd[J];                                                      \
        {                                                                     \
            int d_up = dpp_i<0x111>(-1, d_l);                                 \
            float msk = (d_up == d_l) ? 1.0f : 0.0f;                          \
            _Pragma("unroll")                                                 \
            for (int c = 0; c < 16; ++c) {                                    \
                float vu = __int_as_float(                                    \
                    dpp_i<0x111>(0, __float_as_int(vals[c])));                \
                vals[c] = fmaf(vu, msk, vals[c]);                             \
            }                                                                 \
        }                                                                     \
        {                                                                     \
            int d_up = dpp_i<0x112>(-1, d_l);                                 \
            float msk = (d_up == d_l) ? 1.0f : 0.0f;                          \
            _Pragma("unroll")                                                 \
            for (int c = 0; c < 16; ++c) {                                    \
                float vu = __int_as_float(                                    \
                    dpp_i<0x112>(0, __float_as_int(vals[c])));                \
                vals[c] = fmaf(vu, msk, vals[c]);                             \
            }                                                                 \
        }                                                                     \
        {                                                                     \
            int d_up = dpp_i<0x114>(-1, d_l);                                 \
            float msk = (d_up == d_l) ? 1.0f : 0.0f;                          \
            _Pragma("unroll")                                                 \
            for (int c = 0; c < 16; ++c) {                                    \
                float vu = __int_as_float(                                    \
                    dpp_i<0x114>(0, __float_as_int(vals[c])));                \
                vals[c] = fmaf(vu, msk, vals[c]);                             \
            }                                                                 \
        }                                                                     \
        {                                                                     \
            int d_up = dpp_i<0x118>(-1, d_l);                                 \
            float msk = (d_up == d_l) ? 1.0f : 0.0f;                          \
            _Pragma("unroll")                                                 \
            for (int c = 0; c < 16; ++c) {                                    \
                float vu = __int_as_float(                                    \
                    dpp_i<0x118>(0, __float_as_int(vals[c])));                \
                vals[c] = fmaf(vu, msk, vals[c]);                             \
            }                                                                 \
        }                                                                     \
        if ((J) > 0) {  /* carry in from previous window's trailing segment */\
            int prevd = __shfl(pd[(J) > 0 ? (J) - 1 : 0], rowb | 15);         \
            float mk = (d_l == prevd) ? 1.0f : 0.0f;                          \
            _Pragma("unroll")                                                 \
            for (int c = 0; c < 16; ++c) {                                    \
                float cv = __shfl(prevv[c], rowb | 15);                       \
                vals[c] = fmaf(cv, mk, vals[c]);                              \
            }                                                                 \
        }                                                                     \
        _Pragma("unroll")                                                     \
        for (int c = 0; c < 16; ++c) prevv[c] = vals[c];                      \
        int nd = dpp_i<0x101>(-1, d_l);  /* lane i <- lane i+1; l15 -> -1 */  \
        if ((J) < 3) {  /* lookahead: suppress atomic if segment continues */ \
            int nx = __shfl(pd[(J) < 3 ? (J) + 1 : 3], rowb);                 \
            nd = (l15 == 15) ? nx : nd;                                       \
        }                                                                     \
        bool last = (nd != d_l);                                              \
        if (last) {                                                           \
            _Pragma("unroll")                                                 \
            for (int mt = 0; mt < 4; ++mt) {                                  \
                _Pragma("unroll")                                             \
                for (int r = 0; r < 4; ++r) {                                 \
                    int ch = mt * 16 + quad * 4 + r;                          \
                    atomicAdd(&agg[(size_t)d_l * 64 + ch], vals[mt * 4 + r]); \
                }                                                             \
            }                                                                 \
        }                                                                     \
    }
    FINISH(0)
    FINISH(1)
    FINISH(2)
    FINISH(3)
#undef FINISH
}

// ---------------------------------------------------------------------------
// Node MLP via MFMA + residual: h = h + LN(silu([h,agg]@W1+b1)@W2+b2)
// R22: after consuming agg (each element read exactly once per layer: rows
// l15, channels quad*8 / 32+quad*8 cover the full 16x64 tile), the lane
// stores ZEROS back -- this replaces the per-layer 12.8 MB hipMemsetAsync
// (5 stream-serialized dispatches). Guarded n < NN: clamped tail lanes
// must not zero node NN-1's row before its rightful wave reads it.
// ---------------------------------------------------------------------------
__global__ __launch_bounds__(256, 6) void node_kernel(
    float* __restrict__ h, unsigned int* __restrict__ h2,
    float* __restrict__ agg,
    const short* __restrict__ W1pk, const float* __restrict__ b1,
    const short* __restrict__ W2pk, const float* __restrict__ b2,
    const float* __restrict__ g, const float* __restrict__ be)
{
    __shared__ unsigned int lds[4 * 576];
    const int lane = threadIdx.x & 63;
    const int w    = threadIdx.x >> 6;
    const int quad = lane >> 4;
    const int l15  = lane & 15;
    const int n0   = blockIdx.x * 64 + w * 16;     // this wave's 16 nodes
    unsigned int* MID = lds + w * 576;             // 16 rows x 36 words

    int n_l = n0 + l15; if (n_l >= NN) n_l = NN - 1;   // tail clamp (discarded)

    // direct B-fragments: h2 channels [quad*8..+7] (ks0) / [32+quad*8..] (ks1)
    const unsigned int* nrow = h2 + (size_t)n_l * 32 + quad * 4;
    union { uint4 u; bf16x8 b; } bfA, bfB;
    bfA.u = *(const uint4*)(nrow);
    bfB.u = *(const uint4*)(nrow + 16);
    // agg channels [quad*8..+7] (ks2) / [32+quad*8..] (ks3), fp32 -> bf16
    float* ap = agg + (size_t)n_l * 64 + quad * 8;
    float4 a0 = *(const float4*)(ap);
    float4 a1 = *(const float4*)(ap + 4);
    float4 a2 = *(const float4*)(ap + 32);
    float4 a3 = *(const float4*)(ap + 36);
    union { unsigned int u[4]; bf16x8 b; } bfC, bfD;
    bfC.u[0] = pack_bf16x2(a0.x, a0.y); bfC.u[1] = pack_bf16x2(a0.z, a0.w);
    bfC.u[2] = pack_bf16x2(a1.x, a1.y); bfC.u[3] = pack_bf16x2(a1.z, a1.w);
    bfD.u[0] = pack_bf16x2(a2.x, a2.y); bfD.u[1] = pack_bf16x2(a2.z, a2.w);
    bfD.u[2] = pack_bf16x2(a3.x, a3.y); bfD.u[3] = pack_bf16x2(a3.z, a3.w);
    // zero agg in-place for the next layer's atomics (replaces memset);
    // same addresses just loaded -> ordered within the lane.
    if (n0 + l15 < NN) {
        const float4 z = {0.f, 0.f, 0.f, 0.f};
        *(float4*)(ap)      = z;
        *(float4*)(ap + 4)  = z;
        *(float4*)(ap + 32) = z;
        *(float4*)(ap + 36) = z;
    }

    // GEMM1: K=128 (4 ks)
    f32x4 acc1[4] = {{0,0,0,0},{0,0,0,0},{0,0,0,0},{0,0,0,0}};
#define G1_STEP(KS, BFRAG)                                                    \
    {                                                                         \
        const short* apk = W1pk + (size_t)((KS) * 4) * 512 + lane * 8;        \
        _Pragma("unroll")                                                     \
        for (int mt = 0; mt < 4; ++mt) {                                      \
            bf16x8 afrag = *(const bf16x8*)(apk + mt * 512);                  \
            acc1[mt] = __builtin_amdgcn_mfma_f32_16x16x32_bf16(               \
                afrag, BFRAG, acc1[mt], 0, 0, 0);                             \
        }                                                                     \
    }
    G1_STEP(0, bfA.b)
    G1_STEP(1, bfB.b)
    G1_STEP(2, bfC.b)
    G1_STEP(3, bfD.b)
#undef G1_STEP

#pragma unroll
    for (int mt = 0; mt < 4; ++mt) {
        int ch0 = mt * 16 + quad * 4;
        float v0 = silu_f(acc1[mt][0] + b1[ch0 + 0]);
        float v1 = silu_f(acc1[mt][1] + b1[ch0 + 1]);
        float v2 = silu_f(acc1[mt][2] + b1[ch0 + 2]);
        float v3 = silu_f(acc1[mt][3] + b1[ch0 + 3]);
        uint2 pk;
        pk.x = pack_bf16x2(v0, v1);
        pk.y = pack_bf16x2(v2, v3);
        *(uint2*)(MID + l15 * 36 + mt * 8 + quad * 2) = pk;
    }

    // GEMM2: K=64 (2 ks)
    f32x4 acc2[4] = {{0,0,0,0},{0,0,0,0},{0,0,0,0},{0,0,0,0}};
    const unsigned int* mrow = MID + l15 * 36;
    for (int ks = 0; ks < 2; ++ks) {
        bf16x8 bfrag = *(const bf16x8*)(mrow + ks * 16 + quad * 4);
        const short* apk = W2pk + (size_t)(ks * 4) * 512 + lane * 8;
#pragma unroll
        for (int mt = 0; mt < 4; ++mt) {
            bf16x8 afrag = *(const bf16x8*)(apk + mt * 512);
            acc2[mt] = __builtin_amdgcn_mfma_f32_16x16x32_bf16(
                afrag, bfrag, acc2[mt], 0, 0, 0);
        }
    }

    // bias + LN over the 64 channels of this lane's node
    float vals[16];
    float s1 = 0.f, s2 = 0.f;
#pragma unroll
    for (int mt = 0; mt < 4; ++mt) {
#pragma unroll
        for (int r = 0; r < 4; ++r) {
            int ch = mt * 16 + quad * 4 + r;
            float vv = acc2[mt][r] + b2[ch];
            vals[mt * 4 + r] = vv;
            s1 += vv; s2 += vv * vv;
        }
    }
    s1 += __shfl_xor(s1, 16); s1 += __shfl_xor(s1, 32);
    s2 += __shfl_xor(s2, 16); s2 += __shfl_xor(s2, 32);
    float mean = s1 * (1.0f / 64.0f);
    float var  = s2 * (1.0f / 64.0f) - mean * mean;
    float rstd = rsqrtf(var + 1e-5f);

    int n = n0 + l15;
    if (n < NN) {
#pragma unroll
        for (int mt = 0; mt < 4; ++mt) {
            int ch0 = mt * 16 + quad * 4;
            float4 hv = *(const float4*)(h + (size_t)n * 64 + ch0);
            float o0 = hv.x + (vals[mt*4+0] - mean) * rstd * g[ch0+0] + be[ch0+0];
            float o1 = hv.y + (vals[mt*4+1] - mean) * rstd * g[ch0+1] + be[ch0+1];
            float o2 = hv.z + (vals[mt*4+2] - mean) * rstd * g[ch0+2] + be[ch0+2];
            float o3 = hv.w + (vals[mt*4+3] - mean) * rstd * g[ch0+3] + be[ch0+3];
            float4 st = {o0, o1, o2, o3};
            *(float4*)(h + (size_t)n * 64 + ch0) = st;
            uint2 pk;
            pk.x = pack_bf16x2(o0, o1);
            pk.y = pack_bf16x2(o2, o3);
            *(uint2*)(h2 + (size_t)n * 32 + mt * 8 + quad * 2) = pk;
        }
    }
}

// ---------------------------------------------------------------------------
// Local decoder via MFMA: out_local = silu(h @ W1 + b1) @ W2 + b2 -> [NN, 6]
// ---------------------------------------------------------------------------
__global__ __launch_bounds__(256, 7) void dec_local_kernel(
    const unsigned int* __restrict__ h2,
    const short* __restrict__ W1pk, const float* __restrict__ b1,
    const short* __restrict__ W2pk, const float* __restrict__ b2,
    float* __restrict__ out)
{
    __shared__ unsigned int lds[4 * 576];
    const int lane = threadIdx.x & 63;
    const int w    = threadIdx.x >> 6;
    const int quad = lane >> 4;
    const int l15  = lane & 15;
    const int n0   = blockIdx.x * 64 + w * 16;
    unsigned int* MID = lds + w * 576;             // 16 rows x 36 words

    int n_l = n0 + l15; if (n_l >= NN) n_l = NN - 1;
    const unsigned int* nrow = h2 + (size_t)n_l * 32 + quad * 4;
    union { uint4 u; bf16x8 b; } bfA, bfB;
    bfA.u = *(const uint4*)(nrow);
    bfB.u = *(const uint4*)(nrow + 16);

    // GEMM1: K=64 (2 ks), M=64 (4 mt)
    f32x4 acc1[4] = {{0,0,0,0},{0,0,0,0},{0,0,0,0},{0,0,0,0}};
#define G1_STEP(KS, BFRAG)                                                    \
    {                                                                         \
        const short* apk = W1pk + (size_t)((KS) * 4) * 512 + lane * 8;        \
        _Pragma("unroll")                                                     \
        for (int mt = 0; mt < 4; ++mt) {                                      \
            bf16x8 afrag = *(const bf16x8*)(apk + mt * 512);                  \
            acc1[mt] = __builtin_amdgcn_mfma_f32_16x16x32_bf16(               \
                afrag, BFRAG, acc1[mt], 0, 0, 0);                             \
        }                                                                     \
    }
    G1_STEP(0, bfA.b)
    G1_STEP(1, bfB.b)
#undef G1_STEP

    // epilogue: bias + silu -> MID (bf16)
#pragma unroll
    for (int mt = 0; mt < 4; ++mt) {
        int ch0 = mt * 16 + quad * 4;
        float v0 = silu_f(acc1[mt][0] + b1[ch0 + 0]);
        float v1 = silu_f(acc1[mt][1] + b1[ch0 + 1]);
        float v2 = silu_f(acc1[mt][2] + b1[ch0 + 2]);
        float v3 = silu_f(acc1[mt][3] + b1[ch0 + 3]);
        uint2 pk;
        pk.x = pack_bf16x2(v0, v1);
        pk.y = pack_bf16x2(v2, v3);
        *(uint2*)(MID + l15 * 36 + mt * 8 + quad * 2) = pk;
    }

    // GEMM2: K=64 (2 ks), M=16 (out padded 6->16)
    f32x4 acc2 = {0, 0, 0, 0};
    const unsigned int* mrow = MID + l15 * 36;
    for (int ks = 0; ks < 2; ++ks) {
        bf16x8 bfrag = *(const bf16x8*)(mrow + ks * 16 + quad * 4);
        bf16x8 afrag = *(const bf16x8*)(W2pk + (size_t)ks * 512 + lane * 8);
        acc2 = __builtin_amdgcn_mfma_f32_16x16x32_bf16(afrag, bfrag, acc2, 0, 0, 0);
    }

    int n = n0 + l15;
    if (n < NN && quad < 2) {
#pragma unroll
        for (int r = 0; r < 4; ++r) {
            int ch = quad * 4 + r;
            if (ch < 6) out[(size_t)n * 6 + ch] = acc2[r] + b2[ch];
        }
    }
}

// ---------------------------------------------------------------------------
// Pooling: pooled[g][c] = sum_{batch[n]==g} h[n][c];  cnt[g] = count
// ---------------------------------------------------------------------------
__global__ __launch_bounds__(256) void pool_kernel(
    const float* __restrict__ h, const int* __restrict__ batch,
    float* __restrict__ pooled, float* __restrict__ cnt)
{
    const int c   = threadIdx.x & 63;
    const int rep = blockIdx.x * 4 + (threadIdx.x >> 6);   // 1024 reps
    float acc[NG] = {0.f, 0.f, 0.f, 0.f};
    float cl[NG]  = {0.f, 0.f, 0.f, 0.f};
    for (int n = rep; n < NN; n += 1024) {
        int b = batch[n];
        float v = h[n * 64 + c];
#pragma unroll
        for (int gph = 0; gph < NG; ++gph) {
            if (b == gph) { acc[gph] += v; cl[gph] += 1.0f; }
        }
    }
#pragma unroll
    for (int gph = 0; gph < NG; ++gph) {
        atomicAdd(&pooled[gph * 64 + c], acc[gph]);
        if (c == 0) atomicAdd(&cnt[gph], cl[gph]);
    }
}

// ---------------------------------------------------------------------------
// Global decoder: out_global = silu(mean_pool @ W1 + b1) @ W2 + b2 -> [4,4]
// ---------------------------------------------------------------------------
__global__ __launch_bounds__(256) void dec_global_kernel(
    const float* __restrict__ pooled, const float* __restrict__ cnt,
    const float* __restrict__ W1, const float* __restrict__ b1,
    const float* __restrict__ W2, const float* __restrict__ b2,
    float* __restrict__ out)
{
    __shared__ float mid_sh[4][32];
    const int lane = threadIdx.x & 63;
    const int gph  = threadIdx.x >> 6;
    float inv = 1.0f / fmaxf(cnt[gph], 1.0f);
    if (lane < 32) {
        float a = b1[lane];
        for (int k = 0; k < 64; ++k)
            a = fmaf(pooled[gph * 64 + k] * inv, W1[k * 32 + lane], a);
        mid_sh[gph][lane] = silu_f(a);
    }
    __syncthreads();
    if (lane < 4) {
        float o = b2[lane];
        for (int k = 0; k < 32; ++k)
            o = fmaf(mid_sh[gph][k], W2[k * 4 + lane], o);
        out[gph * 4 + lane] = o;
    }
}

// ---------------------------------------------------------------------------
extern "C" void kernel_launch(void* const* d_in, const int* in_sizes, int n_in,
                              void* d_out, int out_size, void* d_ws, size_t ws_size,
                              hipStream_t stream)
{
    const float* x      = (const float*)d_in[0];
    const int*   ei     = (const int*)  d_in[1];
    const float* ea     = (const float*)d_in[2];
    const int*   batch  = (const int*)  d_in[3];
    const float* case_p = (const float*)d_in[4];
    const float* bc_p   = (const float*)d_in[5];
    const float* enc_W1 = (const float*)d_in[6];
    const float* enc_b1 = (const float*)d_in[7];
    const float* enc_W2 = (const float*)d_in[8];
    const float* enc_b2 = (const float*)d_in[9];
    const float* enc_g  = (const float*)d_in[10];
    const float* enc_be = (const float*)d_in[11];
    const float* eW1    = (const float*)d_in[12];
    const float* eb1    = (const float*)d_in[13];
    const float* eW2    = (const float*)d_in[14];
    const float* eb2    = (const float*)d_in[15];
    const float* eg     = (const float*)d_in[16];
    const float* ebe    = (const float*)d_in[17];
    const float* nW1    = (const float*)d_in[18];
    const float* nb1    = (const float*)d_in[19];
    const float* nW2    = (const float*)d_in[20];
    const float* nb2    = (const float*)d_in[21];
    const float* ng     = (const float*)d_in[22];
    const float* nbe    = (const float*)d_in[23];
    const float* dlW1   = (const float*)d_in[24];
    const float* dlb1   = (const float*)d_in[25];
    const float* dlW2   = (const float*)d_in[26];
    const float* dlb2   = (const float*)d_in[27];
    const float* dgW1   = (const float*)d_in[28];
    const float* dgb1   = (const float*)d_in[29];
    const float* dgW2   = (const float*)d_in[30];
    const float* dgb2   = (const float*)d_in[31];

    float* out = (float*)d_out;

    char* ws = (char*)d_ws;
    size_t off_b = 0;
    auto alloc = [&](size_t bytes) {
        void* p = ws + off_b;
        off_b = (off_b + bytes + 255) & ~(size_t)255;
        return p;
    };
    const size_t hBytes = (size_t)NN * H * sizeof(float);     // 12.8 MB
    float*        h      = (float*)alloc(hBytes);
    float*        agg    = (float*)alloc(hBytes);
    unsigned int* h2     = (unsigned int*)alloc((size_t)NN * 32 * 4);  // bf16 mirror
    float*        pooled = (float*)alloc(256 * sizeof(float));
    float*        cnt    = (float*)alloc(4 * sizeof(float));
    int*          deg    = (int*)alloc((NN + 1) * sizeof(int));
    int*          offs   = (int*)alloc((NN + 1) * sizeof(int));
    int*          cursor = (int*)alloc((NN + 1) * sizeof(int));
    int*          bsum   = (int*)alloc(64 * sizeof(int));
    int*          bbase  = (int*)alloc(64 * sizeof(int));
    int*          sidx   = (int*)alloc((size_t)NE * sizeof(int));
    int*          sdst   = (int*)alloc((size_t)NE * sizeof(int));
    int*          ssrc   = (int*)alloc((size_t)NE * sizeof(int));
    uint4*        ea_pk  = (uint4*)alloc((size_t)NE * sizeof(uint4));  // 25.6 MB
    short*        eW1pk  = (short*)alloc((size_t)NL * 10240 * sizeof(short));
    short*        eW2pk  = (short*)alloc((size_t)NL * 4096 * sizeof(short));
    short*        nW1pk  = (short*)alloc((size_t)NL * 8192 * sizeof(short));
    short*        nW2pk  = (short*)alloc((size_t)NL * 4096 * sizeof(short));
    short*        dlW1pk = (short*)alloc(4096 * sizeof(short));
    short*        dlW2pk = (short*)alloc(1024 * sizeof(short));

    hipMemsetAsync(pooled, 0, (256 + 4 + 64) * sizeof(float), stream);
    hipMemsetAsync(deg, 0, (NN + 1) * sizeof(int), stream);
    hipMemsetAsync(agg, 0, hBytes, stream);   // once; node_kernel re-zeroes

    const int NB = (NN + 1023) / 1024;   // 49
    degree_kernel<<<(NE + 255) / 256, 256, 0, stream>>>(ei, deg);
    scan1_kernel<<<NB, 1024, 0, stream>>>(deg, offs, bsum);
    scan2_kernel<<<1, 64, 0, stream>>>(bsum, bbase, NB);
    scan3_kernel<<<NB, 1024, 0, stream>>>(offs, bbase, cursor);
    scatter_kernel<<<(NE + 255) / 256, 256, 0, stream>>>(ei, cursor, sidx, sdst, ssrc);
    ea_pack_kernel<<<(NE + 255) / 256, 256, 0, stream>>>(ea, sidx, ea_pk);
    pack_weights_kernel<<<dim3(124, NL), 256, 0, stream>>>(
        eW1, eW2, nW1, nW2, dlW1, dlW2,
        eW1pk, eW2pk, nW1pk, nW2pk, dlW1pk, dlW2pk);

    const int nodeBlocks = (NN + 63) / 64;    // 782
    encoder_kernel<<<nodeBlocks, 256, 0, stream>>>(
        x, batch, case_p, bc_p, enc_W1, enc_b1, enc_W2, enc_b2, enc_g, enc_be,
        h, h2);

    const int edgeBlocks = NE / 256;          // 6250 (4 windows per wave)
    for (int l = 0; l < NL; ++l) {
        edge_kernel<<<edgeBlocks, 256, 0, stream>>>(
            h2, sdst, ssrc, ea_pk,
            eW1pk + (size_t)l * 10240, eb1 + l * H,
            eW2pk + (size_t)l * 4096,  eb2 + l * H,
            eg + l * H, ebe + l * H, agg);
        node_kernel<<<nodeBlocks, 256, 0, stream>>>(
            h, h2, agg,
            nW1pk + (size_t)l * 8192, nb1 + l * H,
            nW2pk + (size_t)l * 4096, nb2 + l * H,
            ng + l * H, nbe + l * H);
    }

    dec_local_kernel<<<nodeBlocks, 256, 0, stream>>>(
        h2, dlW1pk, dlb1, dlW2pk, dlb2, out);
    pool_kernel<<<256, 256, 0, stream>>>(h, batch, pooled, cnt);
    dec_global_kernel<<<1, 256, 0, stream>>>(pooled, cnt, dgW1, dgb1, dgW2, dgb2,
                                             out + (size_t)NN * 6);
}